// Round 1
// baseline (2854.680 us; speedup 1.0000x reference)
//
#include <hip/hip_runtime.h>
#include <hip/hip_bf16.h>
#include <math.h>

#define B_   64
#define C_   64
#define T_   512
#define V_   25
#define K_   3
#define O_   64
#define EPS_ 1e-6f

#define TT1 4
#define S1  (TT1 * V_)   // 100
#define TT2 8
#define S2  (TT2 * V_)   // 200

__device__ __forceinline__ float hswish(float v) {
    return v * fminf(fmaxf(v + 3.0f, 0.0f), 6.0f) * (1.0f / 6.0f);
}

// K0: A_norm[k,i,j] = d[k,i] * |Af+Al|[k,i,j] * d[k,j],
//     d[k,i] = rsqrt(max(sum_j |Af+Al|[k,i,j], EPS))
__global__ void k0_anorm(const float* __restrict__ Af, const float* __restrict__ Al,
                         float* __restrict__ An) {
    __shared__ float Aabs[K_ * V_ * V_];
    __shared__ float d[K_ * V_];
    int tid = threadIdx.x;
    for (int i = tid; i < K_ * V_ * V_; i += blockDim.x)
        Aabs[i] = fabsf(Af[i] + Al[i]);
    __syncthreads();
    for (int r = tid; r < K_ * V_; r += blockDim.x) {
        float s = 0.0f;
        for (int j = 0; j < V_; j++) s += Aabs[r * V_ + j];
        d[r] = rsqrtf(fmaxf(s, EPS_));
    }
    __syncthreads();
    for (int i = tid; i < K_ * V_ * V_; i += blockDim.x) {
        int k = i / (V_ * V_);
        int rem = i % (V_ * V_);
        int r = rem / V_, cj = rem % V_;
        An[i] = d[k * V_ + r] * Aabs[i] * d[k * V_ + cj];
    }
}

// K1: y[b,o,t,w] = hswish( (1/K) * sum_k sum_c W[k,o,c] * (sum_v x[b,c,t,v]*An[k,v,w]) * gs[o] + gb[o] )
// block: 256 threads, handles one b and TT1=4 consecutive t's.
__global__ __launch_bounds__(256) void k1_gcn(
    const float* __restrict__ x, const float* __restrict__ An,
    const float* __restrict__ Wg, const float* __restrict__ gs,
    const float* __restrict__ gb, float* __restrict__ y) {
    __shared__ float xs[C_][S1];   // 25.6 KB
    __shared__ float xa[C_][S1];   // 25.6 KB

    int bid = blockIdx.x;
    int b   = bid / (T_ / TT1);
    int t0  = (bid % (T_ / TT1)) * TT1;
    int tid = threadIdx.x;

    // stage x tile: x[b, c, t0:t0+TT1, :] -> xs[c][s], s = (t-t0)*V + v (contiguous)
    for (int i = tid; i < C_ * S1; i += 256) {
        int c = i / S1, s = i % S1;
        xs[c][s] = x[((size_t)(b * C_ + c) * T_ + t0) * V_ + s];
    }

    int o = tid >> 2;   // 0..63
    int q = tid & 3;    // 0..3; this thread owns s = q + 4*j, j in [0,25)

    float acc[25];
#pragma unroll
    for (int j = 0; j < 25; j++) acc[j] = 0.0f;

    for (int k = 0; k < K_; k++) {
        __syncthreads();   // xs ready (k=0) / previous xa reads done (k>0)
        // xa[c][s] = sum_v xs[c][(s/25)*25 + v] * An[k,v,s%25]
        for (int i = tid; i < C_ * S1; i += 256) {
            int c = i / S1, s = i % S1;
            int base = (s / V_) * V_;
            int w = s % V_;
            const float* Ak = An + (size_t)k * V_ * V_ + w;
            float sum = 0.0f;
#pragma unroll
            for (int v = 0; v < V_; v++) sum += xs[c][base + v] * Ak[v * V_];
            xa[c][s] = sum;
        }
        __syncthreads();
        const float* Wk = Wg + ((size_t)k * O_ + o) * C_;
        for (int c = 0; c < C_; c++) {
            float w = Wk[c];
#pragma unroll
            for (int j = 0; j < 25; j++) acc[j] += w * xa[c][q + 4 * j];
        }
    }

    float sc = gs[o], bi = gb[o];
    float* yb = y + ((size_t)(b * O_ + o) * T_ + t0) * V_;
#pragma unroll
    for (int j = 0; j < 25; j++) {
        float v = acc[j] * (1.0f / (float)K_) * sc + bi;
        yb[q + 4 * j] = hswish(v);
    }
}

// K2: depthwise temporal conv(k=9, pad 4) + BN1 + hswish -> LDS,
//     then pointwise (oc) + BN2 + residual + hswish -> out.
// block: 256 threads, one b and TT2=8 consecutive t's.
__global__ __launch_bounds__(256) void k2_tcn(
    const float* __restrict__ y, const float* __restrict__ x,
    const float* __restrict__ dw, const float* __restrict__ pw,
    const float* __restrict__ s1v, const float* __restrict__ b1v,
    const float* __restrict__ s2v, const float* __restrict__ b2v,
    float* __restrict__ out) {
    __shared__ float th[C_][S2];   // 51.2 KB

    int bid = blockIdx.x;
    int b   = bid / (T_ / TT2);
    int t0  = (bid % (T_ / TT2)) * TT2;
    int tid = threadIdx.x;

    // stage A: th[c][s] = hswish( bn1( sum_dt dw[c,dt]*y[b,c,t0+s/25+dt-4, s%25] ) )
    for (int i = tid; i < C_ * S2; i += 256) {
        int c = i / S2, s = i % S2;
        int tt = t0 + s / V_;
        int v  = s % V_;
        const float* yb = y + (size_t)(b * C_ + c) * T_ * V_;
        float acc = 0.0f;
#pragma unroll
        for (int dt = 0; dt < 9; dt++) {
            int t = tt + dt - 4;
            if (t >= 0 && t < T_) acc += dw[c * 9 + dt] * yb[t * V_ + v];
        }
        float z = acc * s1v[c] + b1v[c];
        th[c][s] = hswish(z);
    }
    __syncthreads();

    int o = tid >> 2;   // 0..63
    int q = tid & 3;    // s = q + 4*j, j in [0,50)

    float acc[50];
#pragma unroll
    for (int j = 0; j < 50; j++) acc[j] = 0.0f;

    const float* pwo = pw + o * C_;
    for (int c = 0; c < C_; c++) {
        float p = pwo[c];
#pragma unroll
        for (int j = 0; j < 50; j++) acc[j] += p * th[c][q + 4 * j];
    }

    float sc = s2v[o], bi = b2v[o];
    const float* xb = x + ((size_t)(b * O_ + o) * T_ + t0) * V_;
    float* ob = out + ((size_t)(b * O_ + o) * T_ + t0) * V_;
#pragma unroll
    for (int j = 0; j < 50; j++) {
        float z = acc[j] * sc + bi + xb[q + 4 * j];
        ob[q + 4 * j] = hswish(z);
    }
}

extern "C" void kernel_launch(void* const* d_in, const int* in_sizes, int n_in,
                              void* d_out, int out_size, void* d_ws, size_t ws_size,
                              hipStream_t stream) {
    const float* x   = (const float*)d_in[0];
    const float* Af  = (const float*)d_in[1];
    const float* Al  = (const float*)d_in[2];
    const float* Wg  = (const float*)d_in[3];
    const float* gs  = (const float*)d_in[4];
    const float* gb  = (const float*)d_in[5];
    const float* dw  = (const float*)d_in[6];
    const float* pw  = (const float*)d_in[7];
    const float* s1v = (const float*)d_in[8];
    const float* b1v = (const float*)d_in[9];
    const float* s2v = (const float*)d_in[10];
    const float* b2v = (const float*)d_in[11];
    float* out = (float*)d_out;

    float* ws = (float*)d_ws;
    float* An = ws;             // K*V*V = 1875 floats
    float* y  = ws + 4096;      // B*O*T*V = 52,428,800 floats (~210 MB)

    k0_anorm<<<1, 256, 0, stream>>>(Af, Al, An);
    k1_gcn<<<B_ * (T_ / TT1), 256, 0, stream>>>(x, An, Wg, gs, gb, y);
    k2_tcn<<<B_ * (T_ / TT2), 256, 0, stream>>>(y, x, dw, pw, s1v, b1v, s2v, b2v, out);
}

// Round 2
// 609.286 us; speedup vs baseline: 4.6853x; 4.6853x over previous
//
#include <hip/hip_runtime.h>
#include <math.h>

typedef unsigned short ushort_t;
typedef __attribute__((ext_vector_type(8))) short short8;
typedef __attribute__((ext_vector_type(4))) short short4v;
typedef __attribute__((ext_vector_type(4))) float f32x4;

#define B_ 64
#define C_ 64
#define T_ 512
#define V_ 25
#define K_ 3
#define O_ 64

__device__ __forceinline__ float hswish(float v) {
    return v * fminf(fmaxf(v + 3.0f, 0.0f), 6.0f) * (1.0f / 6.0f);
}
// round-to-nearest-even fp32 -> bf16 (values are finite, no NaN care)
__device__ __forceinline__ ushort_t f2bf(float f) {
    unsigned u = __float_as_uint(f);
    unsigned r = (u + 0x7FFFu + ((u >> 16) & 1u)) >> 16;
    return (ushort_t)r;
}
__device__ __forceinline__ float bf2f(ushort_t h) {
    return __uint_as_float(((unsigned)h) << 16);
}

// ---------------------------------------------------------------------------
// K0: build packed bf16 operands in workspace:
//   An2T[80][32]  : An2T[kw][v] = A_norm[k][v][w], kw=k*25+w (pad kw>=75, v>=25 -> 0)
//   W2  [64][192] : W2[o][k*64+c] = W_gcn[k][o][c] / 3
//   pw2 [64][64]  : pw2[o][c]    = tcn_pw[o][c]
// ---------------------------------------------------------------------------
__global__ void k0_prep(const float* __restrict__ Af, const float* __restrict__ Al,
                        const float* __restrict__ Wg, const float* __restrict__ pw,
                        ushort_t* __restrict__ An2T, ushort_t* __restrict__ W2,
                        ushort_t* __restrict__ pw2) {
    __shared__ float Aabs[K_ * V_ * V_];
    __shared__ float dsh[K_ * V_];
    int tid = threadIdx.x;
    for (int i = tid; i < K_ * V_ * V_; i += 256) Aabs[i] = fabsf(Af[i] + Al[i]);
    __syncthreads();
    for (int r = tid; r < K_ * V_; r += 256) {
        float s = 0.0f;
        for (int j = 0; j < V_; j++) s += Aabs[r * V_ + j];
        dsh[r] = rsqrtf(fmaxf(s, 1e-6f));
    }
    __syncthreads();
    for (int i = tid; i < 80 * 32; i += 256) {
        int kw = i >> 5, v = i & 31;
        float val = 0.0f;
        if (kw < 75 && v < 25) {
            int k = (kw >= 50) ? 2 : (kw >= 25 ? 1 : 0);
            int w = kw - k * 25;
            val = dsh[k * 25 + v] * Aabs[(k * 25 + v) * 25 + w] * dsh[k * 25 + w];
        }
        An2T[i] = f2bf(val);
    }
    for (int i = tid; i < 64 * 192; i += 256) {
        int o = i / 192, kc = i % 192;
        int k = kc >> 6, c = kc & 63;
        W2[i] = f2bf(Wg[(k * 64 + o) * 64 + c] * (1.0f / 3.0f));
    }
    for (int i = tid; i < 64 * 64; i += 256) pw2[i] = f2bf(pw[i]);
}

// ---------------------------------------------------------------------------
// K1: GCN, full MFMA. One block = one (b, 4 t's). 256 threads = 4 waves.
// stage1: xa[(c,t) 256 x kw 80] = x-tile[256 x 32pad] @ An2[32 x 80]   (MFMA, 16 Mt x 5 Nt)
//         -> LDS xa2[tw 112pad][kc 192 (+8 pad)] bf16
// stage2: y[o 64 x tw 112pad] = W2[64 x 192] @ xa2[192 x tw]           (MFMA, 4 Mt x 7 Nt x 6 Kt)
//         epilogue BN+hswish -> y bf16 [b][tv][o]
// ---------------------------------------------------------------------------
__global__ __launch_bounds__(256) void k1_gcn(
    const float* __restrict__ x, const ushort_t* __restrict__ An2T,
    const ushort_t* __restrict__ W2, const float* __restrict__ gs,
    const float* __restrict__ gb, ushort_t* __restrict__ y) {
    __shared__ ushort_t xa2[112 * 200];   // 44.8 KB -> 3 blocks/CU

    int bid = blockIdx.x;
    int b = bid >> 7;
    int t0 = (bid & 127) * 4;
    int tid = threadIdx.x;
    int wave = tid >> 6, lane = tid & 63;
    int m16 = lane & 15, g = lane >> 4;

    // register-resident B-frags of An2 (5 N-tiles): B[v=g*8+j][kw=n*16+m16]
    short8 bfA[5];
#pragma unroll
    for (int n = 0; n < 5; n++)
        bfA[n] = *(const short8*)(An2T + (n * 16 + m16) * 32 + g * 8);
    // register-resident A-frags of W2 (this wave's 16-o tile, 6 K-tiles)
    short8 afW[6];
#pragma unroll
    for (int kt = 0; kt < 6; kt++)
        afW[kt] = *(const short8*)(W2 + (wave * 16 + m16) * 192 + kt * 32 + g * 8);

    // ---- stage 1 ----
    int v0 = g * 8;
    for (int mt = 0; mt < 4; mt++) {
        int Mt = wave * 4 + mt;
        int ct = Mt * 16 + m16;          // row index = c*4 + t
        int c = ct >> 2, t = ct & 3;
        const float* gx = x + ((size_t)(b * 64 + c) * 512 + t0 + t) * 25;
        short8 af;
#pragma unroll
        for (int j = 0; j < 8; j++) {
            int v = v0 + j;
            float f = (v < 25) ? gx[v] : 0.0f;
            af[j] = (short)f2bf(f);
        }
        f32x4 acc[5];
#pragma unroll
        for (int n = 0; n < 5; n++) {
            acc[n] = (f32x4){0.f, 0.f, 0.f, 0.f};
            acc[n] = __builtin_amdgcn_mfma_f32_16x16x32_bf16(af, bfA[n], acc[n], 0, 0, 0);
        }
        // D layout: col kw = n*16+m16, row ct = Mt*16 + g*4 + r  => c = Mt*4+g, t = r
        int cc = Mt * 4 + g;
#pragma unroll
        for (int n = 0; n < 5; n++) {
            int kw = n * 16 + m16;
            if (kw < 75) {
                int k = (kw >= 50) ? 2 : (kw >= 25 ? 1 : 0);
                int w = kw - k * 25;
#pragma unroll
                for (int r = 0; r < 4; r++)
                    xa2[(r * 25 + w) * 200 + k * 64 + cc] = f2bf(acc[n][r]);
            }
        }
    }
    __syncthreads();

    // ---- stage 2 ----
    f32x4 gs4 = *(const f32x4*)(gs + wave * 16 + g * 4);
    f32x4 gb4 = *(const f32x4*)(gb + wave * 16 + g * 4);
    for (int nt = 0; nt < 7; nt++) {
        int tw = nt * 16 + m16;
        f32x4 acc = (f32x4){0.f, 0.f, 0.f, 0.f};
#pragma unroll
        for (int kt = 0; kt < 6; kt++) {
            short8 bf = *(const short8*)(xa2 + tw * 200 + kt * 32 + g * 8);
            acc = __builtin_amdgcn_mfma_f32_16x16x32_bf16(afW[kt], bf, acc, 0, 0, 0);
        }
        if (tw < 100) {
            short4v pack;
#pragma unroll
            for (int r = 0; r < 4; r++) {
                float z = acc[r] * gs4[r] + gb4[r];
                pack[r] = (short)f2bf(hswish(z));
            }
            // y bf16 layout [b][tv][o], o = wave*16 + g*4 + r (4 consecutive)
            *(short4v*)(y + ((size_t)b * 12800 + t0 * 25 + tw) * 64 + wave * 16 + g * 4) = pack;
        }
    }
}

// ---------------------------------------------------------------------------
// K2: TCN. One block = one (b, 8 t's). 256 threads = 4 waves.
// phase A: stage y window (16 t x 25 v rows, pitch 72) to LDS (b128, zero halo)
// phase B: depthwise k=9 + BN1 + hswish in registers (4 ch/thread, b64 reads)
// phase C: th overwrites same LDS buffer [tv 200][72] bf16
// phase D: pointwise 64x64 MFMA + BN2 + residual + hswish -> out fp32
// ---------------------------------------------------------------------------
__global__ __launch_bounds__(256) void k2_tcn(
    const ushort_t* __restrict__ y, const float* __restrict__ x,
    const float* __restrict__ dw, const ushort_t* __restrict__ pw2,
    const float* __restrict__ s1v, const float* __restrict__ b1v,
    const float* __restrict__ s2v, const float* __restrict__ b2v,
    float* __restrict__ out) {
    __shared__ ushort_t ys[400 * 72];   // 57.6 KB -> 2 blocks/CU (reused for th)

    int bid = blockIdx.x;
    int b = bid >> 6;
    int t0 = (bid & 63) * 8;
    int tid = threadIdx.x;
    int wave = tid >> 6, lane = tid & 63;
    int m16 = lane & 15, g = lane >> 4;

    // ---- phase A: stage window rows [t0*25-100, t0*25+300) ----
    const ushort_t* yb = y + (size_t)b * 12800 * 64;
    int tvbase = t0 * 25 - 100;
#pragma unroll
    for (int i = 0; i < 13; i++) {
        int li = tid + 256 * i;          // 3200 x short8 total
        if (li < 3200) {
            int row = li >> 3;
            int col = (li & 7) * 8;
            int tvg = tvbase + row;
            short8 val = (short8){0, 0, 0, 0, 0, 0, 0, 0};
            if (tvg >= 0 && tvg < 12800)
                val = *(const short8*)(yb + (size_t)tvg * 64 + col);
            *(short8*)(ys + row * 72 + col) = val;
        }
    }
    __syncthreads();

    // ---- phase B: depthwise into registers ----
    int cg = tid & 15, c0 = cg * 4;
    float dwc[4][9], s1r[4], b1r[4];
#pragma unroll
    for (int cj = 0; cj < 4; cj++) {
#pragma unroll
        for (int dt = 0; dt < 9; dt++) dwc[cj][dt] = dw[(c0 + cj) * 9 + dt];
        s1r[cj] = s1v[c0 + cj];
        b1r[cj] = b1v[c0 + cj];
    }
    short4v thv[13];
#pragma unroll
    for (int i = 0; i < 13; i++) {
        int tv = (tid >> 4) + 16 * i;
        float a0 = 0, a1 = 0, a2 = 0, a3 = 0;
        if (tv < 200) {
#pragma unroll
            for (int dt = 0; dt < 9; dt++) {
                short4v yv = *(const short4v*)(ys + (tv + dt * 25) * 72 + c0);
                a0 += dwc[0][dt] * bf2f((ushort_t)yv[0]);
                a1 += dwc[1][dt] * bf2f((ushort_t)yv[1]);
                a2 += dwc[2][dt] * bf2f((ushort_t)yv[2]);
                a3 += dwc[3][dt] * bf2f((ushort_t)yv[3]);
            }
        }
        short4v p;
        p[0] = (short)f2bf(hswish(a0 * s1r[0] + b1r[0]));
        p[1] = (short)f2bf(hswish(a1 * s1r[1] + b1r[1]));
        p[2] = (short)f2bf(hswish(a2 * s1r[2] + b1r[2]));
        p[3] = (short)f2bf(hswish(a3 * s1r[3] + b1r[3]));
        thv[i] = p;
    }
    __syncthreads();   // all ys reads complete before overwrite

    // ---- phase C: th[tv][72] into same buffer ----
#pragma unroll
    for (int i = 0; i < 13; i++) {
        int tv = (tid >> 4) + 16 * i;
        if (tv < 200) *(short4v*)(ys + tv * 72 + c0) = thv[i];
    }
    __syncthreads();

    // ---- phase D: pointwise MFMA + epilogue ----
    short8 afP[2];
#pragma unroll
    for (int kt = 0; kt < 2; kt++)
        afP[kt] = *(const short8*)(pw2 + (wave * 16 + m16) * 64 + kt * 32 + g * 8);
    f32x4 s2_4 = *(const f32x4*)(s2v + wave * 16 + g * 4);
    f32x4 b2_4 = *(const f32x4*)(b2v + wave * 16 + g * 4);
    for (int nt = 0; nt < 13; nt++) {
        int tw = nt * 16 + m16;
        int twc = (tw < 200) ? tw : 199;   // clamped read; garbage cols masked at store
        f32x4 acc = (f32x4){0.f, 0.f, 0.f, 0.f};
#pragma unroll
        for (int kt = 0; kt < 2; kt++) {
            short8 bf = *(const short8*)(ys + twc * 72 + kt * 32 + g * 8);
            acc = __builtin_amdgcn_mfma_f32_16x16x32_bf16(afP[kt], bf, acc, 0, 0, 0);
        }
        if (tw < 200) {
#pragma unroll
            for (int r = 0; r < 4; r++) {
                int o = wave * 16 + g * 4 + r;
                size_t idx = (size_t)(b * 64 + o) * 12800 + t0 * 25 + tw;
                float z = acc[r] * s2_4[r] + b2_4[r] + x[idx];
                out[idx] = hswish(z);
            }
        }
    }
}

extern "C" void kernel_launch(void* const* d_in, const int* in_sizes, int n_in,
                              void* d_out, int out_size, void* d_ws, size_t ws_size,
                              hipStream_t stream) {
    const float* x   = (const float*)d_in[0];
    const float* Af  = (const float*)d_in[1];
    const float* Al  = (const float*)d_in[2];
    const float* Wg  = (const float*)d_in[3];
    const float* gs  = (const float*)d_in[4];
    const float* gb  = (const float*)d_in[5];
    const float* dw  = (const float*)d_in[6];
    const float* pw  = (const float*)d_in[7];
    const float* s1v = (const float*)d_in[8];
    const float* b1v = (const float*)d_in[9];
    const float* s2v = (const float*)d_in[10];
    const float* b2v = (const float*)d_in[11];
    float* out = (float*)d_out;

    ushort_t* An2T = (ushort_t*)d_ws;                       // 80*32
    ushort_t* W2   = An2T + 2560;                           // 64*192
    ushort_t* pw2  = W2 + 12288;                            // 64*64
    ushort_t* ybf  = (ushort_t*)((char*)d_ws + 65536);      // 64*12800*64 bf16 (~105 MB)

    k0_prep<<<1, 256, 0, stream>>>(Af, Al, Wg, pw, An2T, W2, pw2);
    k1_gcn<<<B_ * (T_ / 4), 256, 0, stream>>>(x, An2T, W2, gs, gb, ybf);
    k2_tcn<<<B_ * (T_ / 8), 256, 0, stream>>>(ybf, x, dw, pw2, s1v, b1v, s2v, b2v, out);
}